// Round 6
// baseline (194.555 us; speedup 1.0000x reference)
//
#include <hip/hip_runtime.h>
#include <hip/hip_bf16.h>
#include <cstdint>

// ---------------------------------------------------------------------------
// GNN encoder: 3 x { agg = segment_sum(z[src], dst); h = z + agg;
//                    t = relu(h@w1+b1); z = relu(t@w2+b2) }
// CSR build per call (no float atomics). z kept in bf16 between layers.
// agg: feature-sliced gather (slice -> one XCD -> L2-resident), nodes
// processed in DEGREE-SORTED order (kills wave divergence: a wave's 16 nodes
// have ~equal degree), 8 independent accumulator chains for ILP.
// MLP: both GEMMs of a layer fused; t lives in LDS.
// ---------------------------------------------------------------------------

#define NNODES 10000
#define NEDGES 320000
#define DIN 128
#define DH 256
#define EBLK 1250   // NEDGES/256
#define NBLK 40     // ceil(NNODES/256)

typedef __bf16 bf16x8 __attribute__((ext_vector_type(8)));
typedef unsigned short ushort8v __attribute__((ext_vector_type(8)));
typedef unsigned short ushort4v __attribute__((ext_vector_type(4)));
typedef float f32x4 __attribute__((ext_vector_type(4)));

__device__ __forceinline__ unsigned short f2bf(float f) {
    unsigned int u = __float_as_uint(f);
    unsigned int r = u + 0x7fffu + ((u >> 16) & 1u);   // round-to-nearest-even
    return (unsigned short)(r >> 16);
}
__device__ __forceinline__ float bf2f(unsigned short u) {
    return __uint_as_float(((unsigned int)u) << 16);
}

// --- fused prep: [0,40) zero cnt | [40] detect i32/i64 | [41,1291) xconv |
// [1291,2699) wconv (6 matrices, fp32 [K][256] -> bf16 [256][K])
struct PrepArgs {
    const float* wsrc[6];
    unsigned short* wdst[6];
    int wkbits[6];
    const int* eb;
    int* flag;
    int* cnt;
    const float* x;
    unsigned short* xb;
};
#define PREP_ZERO_B 40
#define PREP_XCONV_B 1250
#define PREP_WCONV_B 1408
#define PREP_GRID (PREP_ZERO_B + 1 + PREP_XCONV_B + PREP_WCONV_B)

__global__ void prep_kernel(PrepArgs a) {
    int bid = blockIdx.x;
    int tid = threadIdx.x;
    if (bid < PREP_ZERO_B) {
        int i = bid * 256 + tid;
        if (i < NNODES) a.cnt[i] = 0;
    } else if (bid == PREP_ZERO_B) {
        __shared__ int any;
        if (tid == 0) any = 0;
        __syncthreads();
        for (int i = tid; i < 1024; i += 256)
            if (a.eb[2 * i + 1] != 0) any = 1;
        __syncthreads();
        if (tid == 0) a.flag[0] = any;   // 1 => int32 storage, 0 => int64
    } else if (bid < PREP_ZERO_B + 1 + PREP_XCONV_B) {
        int i = (bid - PREP_ZERO_B - 1) * 256 + tid;
        if (i < NNODES * DIN / 4) {
            float4 v = reinterpret_cast<const float4*>(a.x)[i];
            ushort4v o = {f2bf(v.x), f2bf(v.y), f2bf(v.z), f2bf(v.w)};
            reinterpret_cast<ushort4v*>(a.xb)[i] = o;
        }
    } else {
        int wb = bid - (PREP_ZERO_B + 1 + PREP_XCONV_B);
        int m, wblock;
        if (wb < 128) { m = 0; wblock = wb; }
        else { m = 1 + (wb - 128) / 256; wblock = (wb - 128) & 255; }
        int kb = a.wkbits[m];
        int K = 1 << kb;
        int idx = wblock * 256 + tid;
        int nn = idx >> kb;         // output row (col of src)
        int kk = idx & (K - 1);     // output col (row of src)
        a.wdst[m][idx] = f2bf(a.wsrc[m][(size_t)kk * 256 + nn]);
    }
}

__device__ __forceinline__ int eload(const int* __restrict__ eb, int is32, long logical_idx) {
    return is32 ? eb[logical_idx] : eb[2 * logical_idx]; // little-endian low word
}

__global__ void hist_kernel(const int* __restrict__ eb, const int* __restrict__ flag,
                            int* __restrict__ cnt, int E) {
    int i = blockIdx.x * blockDim.x + threadIdx.x;
    if (i >= E) return;
    int is32 = flag[0];
    int d = eload(eb, is32, (long)E + i);
    atomicAdd(&cnt[d], 1);
}

// single-block: (a) exclusive scan over N counts -> offs[N+1] + cursor copy,
// (b) 256-bin degree histogram + scan -> dcursor (for degree-sorted perm).
__global__ __launch_bounds__(1024) void scan_kernel(const int* __restrict__ cnt,
                                                    int* __restrict__ offs,
                                                    int* __restrict__ cursor,
                                                    int* __restrict__ dcursor, int n) {
    __shared__ int sums[1024];
    __shared__ int dbin[256];
    __shared__ int dtmp[256];
    int tid = threadIdx.x;
    if (tid < 256) dbin[tid] = 0;
    __syncthreads();
    int per = (n + 1023) / 1024;          // 10 for n=10000
    int beg = tid * per;
    int local[16];
    int s = 0;
    for (int i = 0; i < per; ++i) {
        int idx = beg + i;
        int v = (idx < n) ? cnt[idx] : 0;
        if (idx < n) atomicAdd(&dbin[v > 255 ? 255 : v], 1);
        local[i] = s;
        s += v;
    }
    sums[tid] = s;
    __syncthreads();
    for (int d = 1; d < 1024; d <<= 1) {
        int y = (tid >= d) ? sums[tid - d] : 0;
        __syncthreads();
        sums[tid] += y;
        __syncthreads();
    }
    int base = sums[tid] - s;             // exclusive prefix of this thread's chunk
    for (int i = 0; i < per; ++i) {
        int idx = beg + i;
        if (idx < n) {
            int v = base + local[i];
            offs[idx] = v;
            cursor[idx] = v;
        }
    }
    if (tid == 1023) offs[n] = sums[1023];
    // degree-bin exclusive scan (Hillis-Steele over 256)
    __syncthreads();
    if (tid < 256) dtmp[tid] = dbin[tid];
    __syncthreads();
    for (int d = 1; d < 256; d <<= 1) {
        int y = 0;
        if (tid < 256 && tid >= d) y = dtmp[tid - d];
        __syncthreads();
        if (tid < 256) dtmp[tid] += y;
        __syncthreads();
    }
    if (tid < 256) dcursor[tid] = dtmp[tid] - dbin[tid];   // exclusive
}

// blocks [0,EBLK): CSR edge scatter; blocks [EBLK,EBLK+NBLK): degree-sorted
// node permutation (perm order within a bin is atomic-order-dependent, but
// the final output is keyed by node id -> bitwise deterministic).
__global__ void scatter_kernel(const int* __restrict__ eb, const int* __restrict__ flag,
                               int* __restrict__ cursor, int* __restrict__ srcs,
                               int* __restrict__ dcursor, const int* __restrict__ cnt,
                               int* __restrict__ perm, int E, int N) {
    int bid = blockIdx.x;
    if (bid < EBLK) {
        int i = bid * 256 + threadIdx.x;
        if (i >= E) return;
        int is32 = flag[0];
        int s = eload(eb, is32, (long)i);
        int d = eload(eb, is32, (long)E + i);
        int pos = atomicAdd(&cursor[d], 1);
        srcs[pos] = s;
    } else {
        int i = (bid - EBLK) * 256 + threadIdx.x;
        if (i >= N) return;
        int deg = cnt[i];
        if (deg > 255) deg = 255;
        int pos = atomicAdd(&dcursor[deg], 1);
        perm[pos] = i;
    }
}

// --- sliced bf16 aggregation over degree-sorted nodes:
// h[i] = z[i] + sum_{e in CSR[i]} z[src_e].
// NSLICE feature slices; slice = bid & (NSLICE-1) -> round-robin XCD binding;
// per-XCD working set N*64B = 0.64 MB (L2-hot). 8 independent gather chains.
template <int D>
__global__ __launch_bounds__(256) void agg_add_sliced_kernel(const unsigned short* __restrict__ z,
                                                             const int* __restrict__ srcs,
                                                             const int* __restrict__ offs,
                                                             const int* __restrict__ perm,
                                                             unsigned short* __restrict__ h, int n) {
    constexpr int NSLICE = (D == 256) ? 8 : 4;
    constexpr int SLICE_E = D / NSLICE;   // 32 elems per slice
    constexpr int LPN = SLICE_E / 8;      // 4 lanes per node (ushort8 each)
    constexpr int NPB = 256 / LPN;        // 64 nodes per block
    int bid = blockIdx.x;
    int slice = bid & (NSLICE - 1);
    int ng = bid / NSLICE;
    int t = threadIdx.x;
    int nidx = ng * NPB + t / LPN;
    if (nidx >= n) return;
    int node = perm[nidx];                // degree-sorted order
    int li = t % LPN;
    int col8 = slice * LPN + li;          // ushort8 column index within row
    const ushort8v* zb = reinterpret_cast<const ushort8v*>(z);
    const int ld8 = D / 8;
    int beg = offs[node], end = offs[node + 1];

    float acc[8][8] = {};                 // [chain][elem] - all static indices
    int e = beg;
    for (; e + 8 <= end; e += 8) {
        ushort8v v[8];
#pragma unroll
        for (int c = 0; c < 8; ++c) v[c] = zb[(size_t)srcs[e + c] * ld8 + col8];
#pragma unroll
        for (int c = 0; c < 8; ++c)
#pragma unroll
            for (int j = 0; j < 8; ++j) acc[c][j] += bf2f(v[c][j]);
    }
    for (; e < end; ++e) {
        ushort8v v = zb[(size_t)srcs[e] * ld8 + col8];
#pragma unroll
        for (int j = 0; j < 8; ++j) acc[0][j] += bf2f(v[j]);
    }
    ushort8v zr = zb[(size_t)node * ld8 + col8];   // residual z term
    ushort8v o;
#pragma unroll
    for (int j = 0; j < 8; ++j) {
        float s = bf2f(zr[j]);
#pragma unroll
        for (int c = 0; c < 8; ++c) s += acc[c][j];
        o[j] = f2bf(s);
    }
    reinterpret_cast<ushort8v*>(h)[(size_t)node * ld8 + col8] = o;
}

// --- fused MLP: C = relu( relu(A@W1+b1) @ W2 + b2 ).
// A: MxK bf16, Wt1: 256xK bf16 (transposed), Wt2: 256x256 bf16 (transposed).
// Block = 64 rows x 256 cols, 4 waves; wave w owns rows w*16..w*16+15 in BOTH
// phases, so t stays in LDS (fragment-ordered Ts). Per wave: 16 f32x4 accs.
// MFMA layouts (m89-verified): A-frag row=lane&15, k=(lane>>4)*8+j;
// C/D col=lane&15, row=(lane>>4)*4+j.
template <int K, int OUT_BF16>
__global__ __launch_bounds__(256) void mlp_fused_kernel(const unsigned short* __restrict__ A,
                                                        const unsigned short* __restrict__ Wt1,
                                                        const float* __restrict__ b1,
                                                        const unsigned short* __restrict__ Wt2,
                                                        const float* __restrict__ b2,
                                                        void* __restrict__ C, int M) {
    __shared__ unsigned short As[4][64][8];      // 4 KB   [kc][row][j]
    __shared__ unsigned short Bs[4][256][8];     // 16 KB  [kc][col][j]
    __shared__ unsigned short Ts[8][4][64][8];   // 32 KB  Ts[a][b][r][c] = t[r][a*32+b*8+c]
    int tid = threadIdx.x;
    int wave = tid >> 6, lane = tid & 63;
    int m0 = blockIdx.x * 64;
    int fr = lane & 15;        // fragment row/col
    int kc = lane >> 4;        // fragment k-chunk (== rg for C/D rows)
    int sr = tid >> 2;         // staging row 0..63
    int scn = tid & 3;         // staging k-chunk 0..3

    f32x4 acc[16];
#pragma unroll
    for (int c = 0; c < 16; ++c) acc[c] = (f32x4){0.f, 0.f, 0.f, 0.f};

    // ---- phase 1: t = relu(A @ W1 + b1), t in Ts
    for (int k0 = 0; k0 < K; k0 += 32) {
        int gr = m0 + sr;
        ushort8v av = {0, 0, 0, 0, 0, 0, 0, 0};
        if (gr < M) av = *reinterpret_cast<const ushort8v*>(&A[(size_t)gr * K + k0 + scn * 8]);
        *reinterpret_cast<ushort8v*>(&As[scn][sr][0]) = av;
#pragma unroll
        for (int cp = 0; cp < 4; ++cp) {
            int col = cp * 64 + sr;
            ushort8v bv = *reinterpret_cast<const ushort8v*>(&Wt1[(size_t)col * K + k0 + scn * 8]);
            *reinterpret_cast<ushort8v*>(&Bs[scn][col][0]) = bv;
        }
        __syncthreads();
        bf16x8 af = __builtin_bit_cast(bf16x8,
            *reinterpret_cast<const ushort8v*>(&As[kc][wave * 16 + fr][0]));
#pragma unroll
        for (int cf = 0; cf < 16; ++cf) {
            bf16x8 bf = __builtin_bit_cast(bf16x8,
                *reinterpret_cast<const ushort8v*>(&Bs[kc][cf * 16 + fr][0]));
            acc[cf] = __builtin_amdgcn_mfma_f32_16x16x32_bf16(af, bf, acc[cf], 0, 0, 0);
        }
        __syncthreads();
    }
    // epilogue 1 -> Ts (scalar b16 writes; one-time cost per block)
#pragma unroll
    for (int cf = 0; cf < 16; ++cf) {
        int col = cf * 16 + fr;
        float bb = b1[col];
#pragma unroll
        for (int j = 0; j < 4; ++j) {
            int row = wave * 16 + kc * 4 + j;
            float v = fmaxf(acc[cf][j] + bb, 0.f);
            Ts[cf >> 1][((cf & 1) << 1) | (fr >> 3)][row][fr & 7] = f2bf(v);
        }
        acc[cf] = (f32x4){0.f, 0.f, 0.f, 0.f};
    }
    __syncthreads();

    // ---- phase 2: z = relu(t @ W2 + b2); A-frags read from own wave's Ts rows
    for (int k20 = 0; k20 < 8; ++k20) {
#pragma unroll
        for (int cp = 0; cp < 4; ++cp) {
            int col = cp * 64 + sr;
            ushort8v bv = *reinterpret_cast<const ushort8v*>(&Wt2[(size_t)col * 256 + k20 * 32 + scn * 8]);
            *reinterpret_cast<ushort8v*>(&Bs[scn][col][0]) = bv;
        }
        __syncthreads();
        bf16x8 af = __builtin_bit_cast(bf16x8,
            *reinterpret_cast<const ushort8v*>(&Ts[k20][kc][wave * 16 + fr][0]));
#pragma unroll
        for (int cf = 0; cf < 16; ++cf) {
            bf16x8 bf = __builtin_bit_cast(bf16x8,
                *reinterpret_cast<const ushort8v*>(&Bs[kc][cf * 16 + fr][0]));
            acc[cf] = __builtin_amdgcn_mfma_f32_16x16x32_bf16(af, bf, acc[cf], 0, 0, 0);
        }
        __syncthreads();
    }
    // epilogue 2 -> global
#pragma unroll
    for (int cf = 0; cf < 16; ++cf) {
        int col = cf * 16 + fr;
        float bb = b2[col];
#pragma unroll
        for (int j = 0; j < 4; ++j) {
            int row = m0 + wave * 16 + kc * 4 + j;
            if (row < M) {
                float v = fmaxf(acc[cf][j] + bb, 0.f);
                if (OUT_BF16)
                    ((unsigned short*)C)[(size_t)row * 256 + col] = f2bf(v);
                else
                    ((float*)C)[(size_t)row * 256 + col] = v;
            }
        }
    }
}

extern "C" void kernel_launch(void* const* d_in, const int* in_sizes, int n_in,
                              void* d_out, int out_size, void* d_ws, size_t ws_size,
                              hipStream_t stream) {
    const float* x = (const float*)d_in[0];
    const int* eb = (const int*)d_in[1];
    const int E = NEDGES;
    const int N = NNODES;

    const float* w1[3] = {(const float*)d_in[2], (const float*)d_in[6], (const float*)d_in[10]};
    const float* b1[3] = {(const float*)d_in[3], (const float*)d_in[7], (const float*)d_in[11]};
    const float* w2[3] = {(const float*)d_in[4], (const float*)d_in[8], (const float*)d_in[12]};
    const float* b2[3] = {(const float*)d_in[5], (const float*)d_in[9], (const float*)d_in[13]};

    // workspace layout
    char* ws = (char*)d_ws;
    size_t off = 0;
    auto alloc = [&](size_t bytes) {
        void* p = ws + off;
        off += (bytes + 255) & ~(size_t)255;
        return p;
    };
    int* flag    = (int*)alloc(4);
    int* cnt     = (int*)alloc((size_t)N * 4);
    int* offs    = (int*)alloc((size_t)(N + 1) * 4);
    int* cursor  = (int*)alloc((size_t)N * 4);
    int* dcursor = (int*)alloc(256 * 4);
    int* perm    = (int*)alloc((size_t)N * 4);
    int* srcs    = (int*)alloc((size_t)E * 4);
    unsigned short* xb   = (unsigned short*)alloc((size_t)N * DIN * 2);
    unsigned short* zbuf = (unsigned short*)alloc((size_t)N * DH * 2);
    unsigned short* hbuf = (unsigned short*)alloc((size_t)N * DH * 2);
    unsigned short* wt[6];
    wt[0] = (unsigned short*)alloc((size_t)DIN * DH * 2);          // w1_0^T: 256x128
    for (int i = 1; i < 6; ++i) wt[i] = (unsigned short*)alloc((size_t)DH * DH * 2);
    (void)ws_size; (void)n_in; (void)out_size; (void)in_sizes;

    // --- fused prep (zero cnt | detect | x->bf16 | weights ->bf16 transposed)
    PrepArgs pa;
    pa.wsrc[0] = w1[0]; pa.wsrc[1] = w2[0]; pa.wsrc[2] = w1[1];
    pa.wsrc[3] = w2[1]; pa.wsrc[4] = w1[2]; pa.wsrc[5] = w2[2];
    for (int i = 0; i < 6; ++i) pa.wdst[i] = wt[i];
    pa.wkbits[0] = 7;
    for (int i = 1; i < 6; ++i) pa.wkbits[i] = 8;
    pa.eb = eb; pa.flag = flag; pa.cnt = cnt; pa.x = x; pa.xb = xb;
    prep_kernel<<<PREP_GRID, 256, 0, stream>>>(pa);

    // --- CSR build + degree-sorted node permutation
    hist_kernel<<<(E + 255) / 256, 256, 0, stream>>>(eb, flag, cnt, E);
    scan_kernel<<<1, 1024, 0, stream>>>(cnt, offs, cursor, dcursor, N);
    scatter_kernel<<<EBLK + NBLK, 256, 0, stream>>>(eb, flag, cursor, srcs,
                                                    dcursor, cnt, perm, E, N);

    int mlp_grid = (N + 63) / 64;               // 157 blocks
    int agg_blocks_256 = ((N + 63) / 64) * 8;   // D=256: 64 nodes/block, 8 slices
    int agg_blocks_128 = ((N + 63) / 64) * 4;   // D=128: 64 nodes/block, 4 slices

    // --- layer 0 (K = 128)
    agg_add_sliced_kernel<128><<<agg_blocks_128, 256, 0, stream>>>(xb, srcs, offs, perm, hbuf, N);
    mlp_fused_kernel<128, 1><<<mlp_grid, 256, 0, stream>>>(hbuf, wt[0], b1[0], wt[1], b2[0], zbuf, N);

    // --- layer 1
    agg_add_sliced_kernel<256><<<agg_blocks_256, 256, 0, stream>>>(zbuf, srcs, offs, perm, hbuf, N);
    mlp_fused_kernel<256, 1><<<mlp_grid, 256, 0, stream>>>(hbuf, wt[2], b1[1], wt[3], b2[1], zbuf, N);

    // --- layer 2 (final output fp32 to d_out)
    agg_add_sliced_kernel<256><<<agg_blocks_256, 256, 0, stream>>>(zbuf, srcs, offs, perm, hbuf, N);
    mlp_fused_kernel<256, 0><<<mlp_grid, 256, 0, stream>>>(hbuf, wt[4], b1[2], wt[5], b2[2], (float*)d_out, N);
}

// Round 7
// 175.553 us; speedup vs baseline: 1.1082x; 1.1082x over previous
//
#include <hip/hip_runtime.h>
#include <hip/hip_bf16.h>
#include <cstdint>

// ---------------------------------------------------------------------------
// GNN encoder: 3 x { agg = segment_sum(z[src], dst); h = z + agg;
//                    t = relu(h@w1+b1); z = relu(t@w2+b2) }
// CSR build per call (no float atomics). z kept in bf16 between layers.
// agg: feature-sliced gather, 128B slices (one cache line per node-slice,
// LPN=8 lanes x 16B), slice->XCD binding keeps working set L2-resident.
// 4-way edge unroll. Degree-sort REVERTED (r6: -8.5us regression).
// MLP: both GEMMs of a layer fused; t lives in LDS.
// ---------------------------------------------------------------------------

#define NNODES 10000
#define NEDGES 320000
#define DIN 128
#define DH 256

typedef __bf16 bf16x8 __attribute__((ext_vector_type(8)));
typedef unsigned short ushort8v __attribute__((ext_vector_type(8)));
typedef unsigned short ushort4v __attribute__((ext_vector_type(4)));
typedef float f32x4 __attribute__((ext_vector_type(4)));

__device__ __forceinline__ unsigned short f2bf(float f) {
    unsigned int u = __float_as_uint(f);
    unsigned int r = u + 0x7fffu + ((u >> 16) & 1u);   // round-to-nearest-even
    return (unsigned short)(r >> 16);
}
__device__ __forceinline__ float bf2f(unsigned short u) {
    return __uint_as_float(((unsigned int)u) << 16);
}

// --- fused prep: [0,40) zero cnt | [40] detect i32/i64 | [41,1291) xconv |
// [1291,2699) wconv (6 matrices, fp32 [K][256] -> bf16 [256][K])
struct PrepArgs {
    const float* wsrc[6];
    unsigned short* wdst[6];
    int wkbits[6];
    const int* eb;
    int* flag;
    int* cnt;
    const float* x;
    unsigned short* xb;
};
#define PREP_ZERO_B 40
#define PREP_XCONV_B 1250
#define PREP_WCONV_B 1408
#define PREP_GRID (PREP_ZERO_B + 1 + PREP_XCONV_B + PREP_WCONV_B)

__global__ void prep_kernel(PrepArgs a) {
    int bid = blockIdx.x;
    int tid = threadIdx.x;
    if (bid < PREP_ZERO_B) {
        int i = bid * 256 + tid;
        if (i < NNODES) a.cnt[i] = 0;
    } else if (bid == PREP_ZERO_B) {
        __shared__ int any;
        if (tid == 0) any = 0;
        __syncthreads();
        for (int i = tid; i < 1024; i += 256)
            if (a.eb[2 * i + 1] != 0) any = 1;
        __syncthreads();
        if (tid == 0) a.flag[0] = any;   // 1 => int32 storage, 0 => int64
    } else if (bid < PREP_ZERO_B + 1 + PREP_XCONV_B) {
        int i = (bid - PREP_ZERO_B - 1) * 256 + tid;
        if (i < NNODES * DIN / 4) {
            float4 v = reinterpret_cast<const float4*>(a.x)[i];
            ushort4v o = {f2bf(v.x), f2bf(v.y), f2bf(v.z), f2bf(v.w)};
            reinterpret_cast<ushort4v*>(a.xb)[i] = o;
        }
    } else {
        int wb = bid - (PREP_ZERO_B + 1 + PREP_XCONV_B);
        int m, wblock;
        if (wb < 128) { m = 0; wblock = wb; }
        else { m = 1 + (wb - 128) / 256; wblock = (wb - 128) & 255; }
        int kb = a.wkbits[m];
        int K = 1 << kb;
        int idx = wblock * 256 + tid;
        int nn = idx >> kb;         // output row (col of src)
        int kk = idx & (K - 1);     // output col (row of src)
        a.wdst[m][idx] = f2bf(a.wsrc[m][(size_t)kk * 256 + nn]);
    }
}

__device__ __forceinline__ int eload(const int* __restrict__ eb, int is32, long logical_idx) {
    return is32 ? eb[logical_idx] : eb[2 * logical_idx]; // little-endian low word
}

__global__ void hist_kernel(const int* __restrict__ eb, const int* __restrict__ flag,
                            int* __restrict__ cnt, int E) {
    int i = blockIdx.x * blockDim.x + threadIdx.x;
    if (i >= E) return;
    int is32 = flag[0];
    int d = eload(eb, is32, (long)E + i);
    atomicAdd(&cnt[d], 1);
}

// single-block exclusive scan over N counts -> offs[N+1], cursor copy
__global__ __launch_bounds__(1024) void scan_kernel(const int* __restrict__ cnt,
                                                    int* __restrict__ offs,
                                                    int* __restrict__ cursor, int n) {
    __shared__ int sums[1024];
    int tid = threadIdx.x;
    int per = (n + 1023) / 1024;          // 10 for n=10000
    int beg = tid * per;
    int local[16];
    int s = 0;
    for (int i = 0; i < per; ++i) {
        int idx = beg + i;
        int v = (idx < n) ? cnt[idx] : 0;
        local[i] = s;
        s += v;
    }
    sums[tid] = s;
    __syncthreads();
    for (int d = 1; d < 1024; d <<= 1) {
        int y = (tid >= d) ? sums[tid - d] : 0;
        __syncthreads();
        sums[tid] += y;
        __syncthreads();
    }
    int base = sums[tid] - s;             // exclusive prefix of this thread's chunk
    for (int i = 0; i < per; ++i) {
        int idx = beg + i;
        if (idx < n) {
            int v = base + local[i];
            offs[idx] = v;
            cursor[idx] = v;
        }
    }
    if (tid == 1023) offs[n] = sums[1023];
}

__global__ void scatter_kernel(const int* __restrict__ eb, const int* __restrict__ flag,
                               int* __restrict__ cursor, int* __restrict__ srcs, int E) {
    int i = blockIdx.x * blockDim.x + threadIdx.x;
    if (i >= E) return;
    int is32 = flag[0];
    int s = eload(eb, is32, (long)i);
    int d = eload(eb, is32, (long)E + i);
    int pos = atomicAdd(&cursor[d], 1);
    srcs[pos] = s;
}

// --- sliced bf16 aggregation: h[i] = z[i] + sum_{e in CSR[i]} z[src_e].
// 128B slices: LPN=8 lanes x ushort8 (16B) = exactly one 128B cache line per
// node-slice (no over-fetch, minimal gather split). NSLICE = D*2/128.
// slice = bid & (NSLICE-1) -> round-robin XCD binding; per-XCD working set
// N*128B = 1.28 MB (L2-resident). 4 independent gather chains for ILP.
template <int D>
__global__ __launch_bounds__(256) void agg_add_sliced_kernel(const unsigned short* __restrict__ z,
                                                             const int* __restrict__ srcs,
                                                             const int* __restrict__ offs,
                                                             unsigned short* __restrict__ h, int n) {
    constexpr int NSLICE = (D * 2) / 128;  // 4 for D=256, 2 for D=128
    constexpr int LPN = 8;                 // 8 lanes x 16B = 128B per node-slice
    constexpr int NPB = 256 / LPN;         // 32 nodes per block
    int bid = blockIdx.x;
    int slice = bid & (NSLICE - 1);
    int ng = bid / NSLICE;
    int t = threadIdx.x;
    int node = ng * NPB + t / LPN;
    if (node >= n) return;
    int li = t % LPN;
    int col8 = slice * LPN + li;          // ushort8 column index within row
    const ushort8v* zb = reinterpret_cast<const ushort8v*>(z);
    const int ld8 = D / 8;
    int beg = offs[node], end = offs[node + 1];

    float a0[8] = {}, a1[8] = {}, a2[8] = {}, a3[8] = {};
    int e = beg;
    for (; e + 4 <= end; e += 4) {
        int s0 = srcs[e], s1 = srcs[e + 1], s2 = srcs[e + 2], s3 = srcs[e + 3];
        ushort8v v0 = zb[(size_t)s0 * ld8 + col8];
        ushort8v v1 = zb[(size_t)s1 * ld8 + col8];
        ushort8v v2 = zb[(size_t)s2 * ld8 + col8];
        ushort8v v3 = zb[(size_t)s3 * ld8 + col8];
#pragma unroll
        for (int j = 0; j < 8; ++j) {
            a0[j] += bf2f(v0[j]);
            a1[j] += bf2f(v1[j]);
            a2[j] += bf2f(v2[j]);
            a3[j] += bf2f(v3[j]);
        }
    }
    for (; e < end; ++e) {
        ushort8v v = zb[(size_t)srcs[e] * ld8 + col8];
#pragma unroll
        for (int j = 0; j < 8; ++j) a0[j] += bf2f(v[j]);
    }
    ushort8v zr = zb[(size_t)node * ld8 + col8];   // residual z term
    ushort8v o;
#pragma unroll
    for (int j = 0; j < 8; ++j) {
        float v = a0[j] + a1[j] + a2[j] + a3[j] + bf2f(zr[j]);
        o[j] = f2bf(v);
    }
    reinterpret_cast<ushort8v*>(h)[(size_t)node * ld8 + col8] = o;
}

// --- fused MLP: C = relu( relu(A@W1+b1) @ W2 + b2 ).
// A: MxK bf16, Wt1: 256xK bf16 (transposed), Wt2: 256x256 bf16 (transposed).
// Block = 64 rows x 256 cols, 4 waves; wave w owns rows w*16..w*16+15 in BOTH
// phases, so t stays in LDS (fragment-ordered Ts). Per wave: 16 f32x4 accs.
// MFMA layouts (m89-verified): A-frag row=lane&15, k=(lane>>4)*8+j;
// C/D col=lane&15, row=(lane>>4)*4+j.
template <int K, int OUT_BF16>
__global__ __launch_bounds__(256) void mlp_fused_kernel(const unsigned short* __restrict__ A,
                                                        const unsigned short* __restrict__ Wt1,
                                                        const float* __restrict__ b1,
                                                        const unsigned short* __restrict__ Wt2,
                                                        const float* __restrict__ b2,
                                                        void* __restrict__ C, int M) {
    __shared__ unsigned short As[4][64][8];      // 4 KB   [kc][row][j]
    __shared__ unsigned short Bs[4][256][8];     // 16 KB  [kc][col][j]
    __shared__ unsigned short Ts[8][4][64][8];   // 32 KB  Ts[a][b][r][c] = t[r][a*32+b*8+c]
    int tid = threadIdx.x;
    int wave = tid >> 6, lane = tid & 63;
    int m0 = blockIdx.x * 64;
    int fr = lane & 15;        // fragment row/col
    int kc = lane >> 4;        // fragment k-chunk (== rg for C/D rows)
    int sr = tid >> 2;         // staging row 0..63
    int scn = tid & 3;         // staging k-chunk 0..3

    f32x4 acc[16];
#pragma unroll
    for (int c = 0; c < 16; ++c) acc[c] = (f32x4){0.f, 0.f, 0.f, 0.f};

    // ---- phase 1: t = relu(A @ W1 + b1), t in Ts
    for (int k0 = 0; k0 < K; k0 += 32) {
        int gr = m0 + sr;
        ushort8v av = {0, 0, 0, 0, 0, 0, 0, 0};
        if (gr < M) av = *reinterpret_cast<const ushort8v*>(&A[(size_t)gr * K + k0 + scn * 8]);
        *reinterpret_cast<ushort8v*>(&As[scn][sr][0]) = av;
#pragma unroll
        for (int cp = 0; cp < 4; ++cp) {
            int col = cp * 64 + sr;
            ushort8v bv = *reinterpret_cast<const ushort8v*>(&Wt1[(size_t)col * K + k0 + scn * 8]);
            *reinterpret_cast<ushort8v*>(&Bs[scn][col][0]) = bv;
        }
        __syncthreads();
        bf16x8 af = __builtin_bit_cast(bf16x8,
            *reinterpret_cast<const ushort8v*>(&As[kc][wave * 16 + fr][0]));
#pragma unroll
        for (int cf = 0; cf < 16; ++cf) {
            bf16x8 bf = __builtin_bit_cast(bf16x8,
                *reinterpret_cast<const ushort8v*>(&Bs[kc][cf * 16 + fr][0]));
            acc[cf] = __builtin_amdgcn_mfma_f32_16x16x32_bf16(af, bf, acc[cf], 0, 0, 0);
        }
        __syncthreads();
    }
    // epilogue 1 -> Ts (scalar b16 writes; one-time cost per block)
#pragma unroll
    for (int cf = 0; cf < 16; ++cf) {
        int col = cf * 16 + fr;
        float bb = b1[col];
#pragma unroll
        for (int j = 0; j < 4; ++j) {
            int row = wave * 16 + kc * 4 + j;
            float v = fmaxf(acc[cf][j] + bb, 0.f);
            Ts[cf >> 1][((cf & 1) << 1) | (fr >> 3)][row][fr & 7] = f2bf(v);
        }
        acc[cf] = (f32x4){0.f, 0.f, 0.f, 0.f};
    }
    __syncthreads();

    // ---- phase 2: z = relu(t @ W2 + b2); A-frags read from own wave's Ts rows
    for (int k20 = 0; k20 < 8; ++k20) {
#pragma unroll
        for (int cp = 0; cp < 4; ++cp) {
            int col = cp * 64 + sr;
            ushort8v bv = *reinterpret_cast<const ushort8v*>(&Wt2[(size_t)col * 256 + k20 * 32 + scn * 8]);
            *reinterpret_cast<ushort8v*>(&Bs[scn][col][0]) = bv;
        }
        __syncthreads();
        bf16x8 af = __builtin_bit_cast(bf16x8,
            *reinterpret_cast<const ushort8v*>(&Ts[k20][kc][wave * 16 + fr][0]));
#pragma unroll
        for (int cf = 0; cf < 16; ++cf) {
            bf16x8 bf = __builtin_bit_cast(bf16x8,
                *reinterpret_cast<const ushort8v*>(&Bs[kc][cf * 16 + fr][0]));
            acc[cf] = __builtin_amdgcn_mfma_f32_16x16x32_bf16(af, bf, acc[cf], 0, 0, 0);
        }
        __syncthreads();
    }
    // epilogue 2 -> global
#pragma unroll
    for (int cf = 0; cf < 16; ++cf) {
        int col = cf * 16 + fr;
        float bb = b2[col];
#pragma unroll
        for (int j = 0; j < 4; ++j) {
            int row = m0 + wave * 16 + kc * 4 + j;
            if (row < M) {
                float v = fmaxf(acc[cf][j] + bb, 0.f);
                if (OUT_BF16)
                    ((unsigned short*)C)[(size_t)row * 256 + col] = f2bf(v);
                else
                    ((float*)C)[(size_t)row * 256 + col] = v;
            }
        }
    }
}

extern "C" void kernel_launch(void* const* d_in, const int* in_sizes, int n_in,
                              void* d_out, int out_size, void* d_ws, size_t ws_size,
                              hipStream_t stream) {
    const float* x = (const float*)d_in[0];
    const int* eb = (const int*)d_in[1];
    const int E = NEDGES;
    const int N = NNODES;

    const float* w1[3] = {(const float*)d_in[2], (const float*)d_in[6], (const float*)d_in[10]};
    const float* b1[3] = {(const float*)d_in[3], (const float*)d_in[7], (const float*)d_in[11]};
    const float* w2[3] = {(const float*)d_in[4], (const float*)d_in[8], (const float*)d_in[12]};
    const float* b2[3] = {(const float*)d_in[5], (const float*)d_in[9], (const float*)d_in[13]};

    // workspace layout
    char* ws = (char*)d_ws;
    size_t off = 0;
    auto alloc = [&](size_t bytes) {
        void* p = ws + off;
        off += (bytes + 255) & ~(size_t)255;
        return p;
    };
    int* flag   = (int*)alloc(4);
    int* cnt    = (int*)alloc((size_t)N * 4);
    int* offs   = (int*)alloc((size_t)(N + 1) * 4);
    int* cursor = (int*)alloc((size_t)N * 4);
    int* srcs   = (int*)alloc((size_t)E * 4);
    unsigned short* xb   = (unsigned short*)alloc((size_t)N * DIN * 2);
    unsigned short* zbuf = (unsigned short*)alloc((size_t)N * DH * 2);
    unsigned short* hbuf = (unsigned short*)alloc((size_t)N * DH * 2);
    unsigned short* wt[6];
    wt[0] = (unsigned short*)alloc((size_t)DIN * DH * 2);          // w1_0^T: 256x128
    for (int i = 1; i < 6; ++i) wt[i] = (unsigned short*)alloc((size_t)DH * DH * 2);
    (void)ws_size; (void)n_in; (void)out_size; (void)in_sizes;

    // --- fused prep (zero cnt | detect | x->bf16 | weights ->bf16 transposed)
    PrepArgs pa;
    pa.wsrc[0] = w1[0]; pa.wsrc[1] = w2[0]; pa.wsrc[2] = w1[1];
    pa.wsrc[3] = w2[1]; pa.wsrc[4] = w1[2]; pa.wsrc[5] = w2[2];
    for (int i = 0; i < 6; ++i) pa.wdst[i] = wt[i];
    pa.wkbits[0] = 7;
    for (int i = 1; i < 6; ++i) pa.wkbits[i] = 8;
    pa.eb = eb; pa.flag = flag; pa.cnt = cnt; pa.x = x; pa.xb = xb;
    prep_kernel<<<PREP_GRID, 256, 0, stream>>>(pa);

    // --- CSR build
    hist_kernel<<<(E + 255) / 256, 256, 0, stream>>>(eb, flag, cnt, E);
    scan_kernel<<<1, 1024, 0, stream>>>(cnt, offs, cursor, N);
    scatter_kernel<<<(E + 255) / 256, 256, 0, stream>>>(eb, flag, cursor, srcs, E);

    int mlp_grid = (N + 63) / 64;               // 157 blocks
    int agg_blocks_256 = ((N + 31) / 32) * 4;   // D=256: 32 nodes/block, 4 slices
    int agg_blocks_128 = ((N + 31) / 32) * 2;   // D=128: 32 nodes/block, 2 slices

    // --- layer 0 (K = 128)
    agg_add_sliced_kernel<128><<<agg_blocks_128, 256, 0, stream>>>(xb, srcs, offs, hbuf, N);
    mlp_fused_kernel<128, 1><<<mlp_grid, 256, 0, stream>>>(hbuf, wt[0], b1[0], wt[1], b2[0], zbuf, N);

    // --- layer 1
    agg_add_sliced_kernel<256><<<agg_blocks_256, 256, 0, stream>>>(zbuf, srcs, offs, hbuf, N);
    mlp_fused_kernel<256, 1><<<mlp_grid, 256, 0, stream>>>(hbuf, wt[2], b1[1], wt[3], b2[1], zbuf, N);

    // --- layer 2 (final output fp32 to d_out)
    agg_add_sliced_kernel<256><<<agg_blocks_256, 256, 0, stream>>>(zbuf, srcs, offs, hbuf, N);
    mlp_fused_kernel<256, 0><<<mlp_grid, 256, 0, stream>>>(hbuf, wt[4], b1[2], wt[5], b2[2], (float*)d_out, N);
}